// Round 7
// baseline (11183.170 us; speedup 1.0000x reference)
//
#include <hip/hip_runtime.h>

typedef unsigned short u16;
typedef _Float16 f16;
typedef __attribute__((ext_vector_type(8))) _Float16 f16x8;
typedef __attribute__((ext_vector_type(8))) unsigned short u16x8;
typedef __attribute__((ext_vector_type(4))) float f32x4;
typedef __attribute__((ext_vector_type(4))) unsigned u32x4;

#define NWG 32

// returns hi f16 bits in [15:0], lo f16 bits (residual * 2048) in [31:16]
__device__ __forceinline__ unsigned split2(float v) {
  f16 h = (f16)v;
  f16 l2 = (f16)((v - (float)h) * 2048.0f);
  return (unsigned)__builtin_bit_cast(u16, h) | ((unsigned)__builtin_bit_cast(u16, l2) << 16);
}

// ---- zero scratch control state (stat partials + flag array) ----
__global__ void k_zero(unsigned* __restrict__ part, unsigned* __restrict__ flg) {
  int i = blockIdx.x * blockDim.x + threadIdx.x;
  if (i < 8192) { part[i] = 0u; flg[i] = 0u; }
}

// ---- transpose+split wx [2][512][2048] fp32 -> wxT hi/lo [2][2048][512] f16 ----
__global__ void k_wsplit(const float* __restrict__ wx, u16* __restrict__ th, u16* __restrict__ tl) {
  __shared__ float tile[32][33];
  int l = blockIdx.z;
  int n0 = blockIdx.x * 32, k0 = blockIdx.y * 32;
  int tx = threadIdx.x, ty = threadIdx.y;
  const float* src = wx + (size_t)l * 512 * 2048;
#pragma unroll
  for (int i = 0; i < 4; ++i)
    tile[ty + i * 8][tx] = src[(size_t)(k0 + ty + i * 8) * 2048 + n0 + tx];
  __syncthreads();
  u16* dh = th + (size_t)l * 2048 * 512;
  u16* dl = tl + (size_t)l * 2048 * 512;
#pragma unroll
  for (int i = 0; i < 4; ++i) {
    unsigned s = split2(tile[tx][ty + i * 8]);
    dh[(size_t)(n0 + ty + i * 8) * 512 + k0 + tx] = (u16)s;
    dl[(size_t)(n0 + ty + i * 8) * 512 + k0 + tx] = (u16)(s >> 16);
  }
}

// ---- pack wh_lo into MFMA-B fragment order: wlo[l][g(32)][q(4)][kc(16)][lane(64)][8] ----
__global__ void k_wlo(const float* __restrict__ wh, u16* __restrict__ wlo) {
  int idx = blockIdx.x * blockDim.x + threadIdx.x; // 262144 total
  int l = idx >> 17;
  int r = idx & 131071;
  int lane = r & 63;
  int fg = r >> 6; // [0,2048)
  int kc = fg & 15, q = (fg >> 4) & 3, g = fg >> 6; // g in [0,32)
  int gcol = g * 16 + (lane & 15) + q * 512;
  int kb = kc * 32 + ((lane >> 4) << 3);
  const float* W = wh + (size_t)l * 512 * 2048;
  u16x8 o;
#pragma unroll
  for (int j = 0; j < 8; ++j)
    o[j] = (u16)(split2(W[(size_t)(kb + j) * 2048 + gcol]) >> 16);
  *(u16x8*)(wlo + (size_t)idx * 8) = o;
}

// ---- split-fp16 GEMM: A fp32 [8192,K] (split on the fly), Bt hi/lo [N,K] f16 -> C fp32 ----
__global__ void __launch_bounds__(256, 1) k_gemm3(const float* __restrict__ A,
                                                  const u16* __restrict__ Bh, const u16* __restrict__ Bl,
                                                  float* __restrict__ C, int N, int K) {
  __shared__ u16 sA[2][128 * 64];
  __shared__ u16 sB[2][128 * 64];
  const int tid = threadIdx.x, l = tid & 63, w = tid >> 6;
  const int bx = blockIdx.x, by = blockIdx.y;
  const int wr = (w >> 1) * 64, wc = (w & 1) * 64;
  f32x4 acc0[4][4] = {}, acc1[4][4] = {};
  for (int k0 = 0; k0 < K; k0 += 64) {
#pragma unroll
    for (int s = 0; s < 4; ++s) {
      int cn = s * 256 + tid;
      int row = cn >> 3;
      int f0 = (cn & 7) * 8;
      int kb = f0 * 2;
      int sw = row * 128 + (kb ^ ((row & 7) << 4));
      const float* ap = A + ((size_t)(by * 128 + row) * K + k0 + f0);
      float4 a0 = *(const float4*)ap, a1 = *(const float4*)(ap + 4);
      float av[8] = {a0.x, a0.y, a0.z, a0.w, a1.x, a1.y, a1.z, a1.w};
      u16x8 ah_, al_;
#pragma unroll
      for (int j = 0; j < 8; ++j) {
        unsigned sp = split2(av[j]);
        ah_[j] = (u16)sp;
        al_[j] = (u16)(sp >> 16);
      }
      *(u16x8*)((char*)sA[0] + sw) = ah_;
      *(u16x8*)((char*)sA[1] + sw) = al_;
      size_t gb = (((size_t)(bx * 128 + row) * K + k0) << 1) + kb;
      *(u16x8*)((char*)sB[0] + sw) = *(const u16x8*)((const char*)Bh + gb);
      *(u16x8*)((char*)sB[1] + sw) = *(const u16x8*)((const char*)Bl + gb);
    }
    __syncthreads();
#pragma unroll
    for (int kc = 0; kc < 2; ++kc) {
      int kb = kc * 64 + (l >> 4) * 16;
      f16x8 ah[4], al[4], bh[4], bl[4];
#pragma unroll
      for (int mt = 0; mt < 4; ++mt) {
        int row = wr + mt * 16 + (l & 15);
        int off = row * 128 + (kb ^ ((row & 7) << 4));
        ah[mt] = *(const f16x8*)((const char*)sA[0] + off);
        al[mt] = *(const f16x8*)((const char*)sA[1] + off);
      }
#pragma unroll
      for (int nt = 0; nt < 4; ++nt) {
        int col = wc + nt * 16 + (l & 15);
        int off = col * 128 + (kb ^ ((col & 7) << 4));
        bh[nt] = *(const f16x8*)((const char*)sB[0] + off);
        bl[nt] = *(const f16x8*)((const char*)sB[1] + off);
      }
#pragma unroll
      for (int mt = 0; mt < 4; ++mt)
#pragma unroll
        for (int nt = 0; nt < 4; ++nt) {
          acc0[mt][nt] = __builtin_amdgcn_mfma_f32_16x16x32_f16(ah[mt], bh[nt], acc0[mt][nt], 0, 0, 0);
          acc1[mt][nt] = __builtin_amdgcn_mfma_f32_16x16x32_f16(ah[mt], bl[nt], acc1[mt][nt], 0, 0, 0);
          acc1[mt][nt] = __builtin_amdgcn_mfma_f32_16x16x32_f16(al[mt], bh[nt], acc1[mt][nt], 0, 0, 0);
        }
    }
    __syncthreads();
  }
#pragma unroll
  for (int mt = 0; mt < 4; ++mt)
#pragma unroll
    for (int nt = 0; nt < 4; ++nt)
#pragma unroll
      for (int j = 0; j < 4; ++j) {
        int row = by * 128 + wr + mt * 16 + ((l >> 4) << 2) + j;
        int col = bx * 128 + wc + nt * 16 + (l & 15);
        C[(size_t)row * N + col] = acc0[mt][nt][j] + acc1[mt][nt][j] * (1.0f / 2048.0f);
      }
}

// ---- in-place fp32 row LayerNorm [rows][2048]: y = (x-mu)*rstd*g + b + bias ----
__global__ void __launch_bounds__(256) k_ln2(float* __restrict__ X, const float* __restrict__ g,
                                             const float* __restrict__ b, const float* __restrict__ bias) {
  const int row = blockIdx.x, tid = threadIdx.x;
  float* rp = X + (size_t)row * 2048 + tid * 8;
  float4 v0 = *(const float4*)rp, v1 = *(const float4*)(rp + 4);
  float x[8] = {v0.x, v0.y, v0.z, v0.w, v1.x, v1.y, v1.z, v1.w};
  float s1 = 0.f, s2 = 0.f;
#pragma unroll
  for (int j = 0; j < 8; ++j) { s1 += x[j]; s2 += x[j] * x[j]; }
#pragma unroll
  for (int m = 1; m <= 32; m <<= 1) { s1 += __shfl_xor(s1, m, 64); s2 += __shfl_xor(s2, m, 64); }
  __shared__ float a1[4], a2[4];
  if ((tid & 63) == 0) { a1[tid >> 6] = s1; a2[tid >> 6] = s2; }
  __syncthreads();
  s1 = a1[0] + a1[1] + a1[2] + a1[3];
  s2 = a2[0] + a2[1] + a2[2] + a2[3];
  float mu = s1 * (1.f / 2048.f);
  float var = s2 * (1.f / 2048.f) - mu * mu;
  float rstd = 1.0f / sqrtf(var + 1e-5f);
#pragma unroll
  for (int j = 0; j < 8; ++j) {
    int c = tid * 8 + j;
    x[j] = (x[j] - mu) * rstd * g[c] + b[c] + bias[c];
  }
  *(float4*)rp = {x[0], x[1], x[2], x[3]};
  *(float4*)(rp + 4) = {x[4], x[5], x[6], x[7]};
}

// ---- persistent LSTM scan (128-step chunk), split-fp16 matmul, flag-array barrier ----
// LN stats: per-WG partial {s1,s2} published as packed u64 stores (no atomics); each WG
// reduces all 32 slots in fixed order after barrier-1 (bit-deterministic). Output-only
// stores (ys/cspill/hn/cn) issued AFTER the barrier-2 flag store so their HBM ack latency
// overlaps the poll. xp(t+1) prefetched in the same shadow.
__global__ void __launch_bounds__(256, 1) k_scan5(
    const float* __restrict__ wh, const u16* __restrict__ wlo,
    const float* __restrict__ gh, const float* __restrict__ bh,
    const float* __restrict__ xn, const float* __restrict__ h0l, const float* __restrict__ c0l,
    unsigned* __restrict__ hpubp, float* __restrict__ cspill,
    unsigned long long* __restrict__ part, unsigned* __restrict__ flags,
    float* __restrict__ ys, float* __restrict__ hn, float* __restrict__ cn,
    int t0, int first) {
  __shared__ u16 pk[32768]; // 64KB: wh_hi fragments [q][kc][lane][8]
  __shared__ float musd[128];
  const int tid = threadIdx.x;
  const int l = tid & 63, w = tid >> 6;
  const int g = blockIdx.x;
  const int lq = l >> 4, ll = l & 15;
  const int hcol = g * 16 + ll;

  for (int c = tid; c < 4096; c += 256) {
    int lane = c & 63, kc = (c >> 6) & 15, q = c >> 10;
    int gcol = g * 16 + (lane & 15) + q * 512;
    int kb = kc * 32 + ((lane >> 4) << 3);
    u16x8 t8;
#pragma unroll
    for (int j = 0; j < 8; ++j)
      t8[j] = __builtin_bit_cast(u16, (f16)wh[(size_t)(kb + j) * 2048 + gcol]);
    *(u16x8*)(pk + (size_t)c * 8) = t8;
  }
  const u16* wloG = wlo + (size_t)g * 32768;
  float gam[4], bet[4];
#pragma unroll
  for (int q = 0; q < 4; ++q) { int gc = hcol + q * 512; gam[q] = gh[gc]; bet[q] = bh[gc]; }
  float cr[4];
#pragma unroll
  for (int j = 0; j < 4; ++j) {
    int r = w * 16 + lq * 4 + j;
    cr[j] = first ? c0l[r * 512 + hcol] : cspill[r * 512 + hcol];
  }
  if (first) {
    for (int u = tid; u < 1024; u += 256) {
      int row = 2 * g + (u >> 9), col = u & 511;
      __hip_atomic_store(&hpubp[row * 512 + col], split2(h0l[row * 512 + col]),
                         __ATOMIC_RELAXED, __HIP_MEMORY_SCOPE_AGENT);
    }
  }
  unsigned bid = 0;
#define BAR_ARRIVE()                                                                         \
  do {                                                                                       \
    bid++;                                                                                   \
    asm volatile("s_waitcnt vmcnt(0)" ::: "memory");                                         \
    __syncthreads();                                                                         \
    if (tid == 0)                                                                            \
      __hip_atomic_store(&flags[g * 32], bid, __ATOMIC_RELAXED, __HIP_MEMORY_SCOPE_AGENT);   \
  } while (0)
#define BAR_WAIT()                                                                           \
  do {                                                                                       \
    if (tid < NWG)                                                                           \
      while (__hip_atomic_load(&flags[tid * 32], __ATOMIC_RELAXED,                           \
                               __HIP_MEMORY_SCOPE_AGENT) < bid) {}                           \
    __builtin_amdgcn_fence(__ATOMIC_ACQUIRE, "agent");                                       \
  } while (0)

  float xp[16];
  BAR_ARRIVE();
  // prefetch xp for t=0 under the initial barrier wait
#pragma unroll
  for (int q = 0; q < 4; ++q)
#pragma unroll
    for (int j = 0; j < 4; ++j)
      xp[q * 4 + j] = xn[(size_t)(w * 16 + lq * 4 + j) * 2048 + hcol + q * 512];
  BAR_WAIT();
  __syncthreads();

  for (int t = 0; t < 128; ++t) {
    const int p = (t0 + t) & 1;
    // ---- phase A: y = h @ W (split fp16), h read as packed u32, unpacked via v_perm ----
    f32x4 acc0[4] = {}, acc1[4] = {};
#pragma unroll
    for (int kc = 0; kc < 16; ++kc) {
      const unsigned* hp = hpubp + ((size_t)(w * 16 + ll) * 512 + kc * 32 + lq * 8);
      uint4 pa = *(const uint4*)hp;
      uint4 pb = *(const uint4*)(hp + 4);
      u32x4 ahw, alw;
      ahw[0] = __builtin_amdgcn_perm(pa.y, pa.x, 0x05040100u);
      ahw[1] = __builtin_amdgcn_perm(pa.w, pa.z, 0x05040100u);
      ahw[2] = __builtin_amdgcn_perm(pb.y, pb.x, 0x05040100u);
      ahw[3] = __builtin_amdgcn_perm(pb.w, pb.z, 0x05040100u);
      alw[0] = __builtin_amdgcn_perm(pa.y, pa.x, 0x07060302u);
      alw[1] = __builtin_amdgcn_perm(pa.w, pa.z, 0x07060302u);
      alw[2] = __builtin_amdgcn_perm(pb.y, pb.x, 0x07060302u);
      alw[3] = __builtin_amdgcn_perm(pb.w, pb.z, 0x07060302u);
      f16x8 ah = __builtin_bit_cast(f16x8, ahw);
      f16x8 al = __builtin_bit_cast(f16x8, alw);
#pragma unroll
      for (int q = 0; q < 4; ++q) {
        f16x8 bhv = *(const f16x8*)(pk + ((size_t)(q * 16 + kc) * 64 + l) * 8);
        f16x8 blv = *(const f16x8*)(wloG + ((size_t)(q * 16 + kc) * 64 + l) * 8);
        acc0[q] = __builtin_amdgcn_mfma_f32_16x16x32_f16(ah, bhv, acc0[q], 0, 0, 0);
        acc1[q] = __builtin_amdgcn_mfma_f32_16x16x32_f16(ah, blv, acc1[q], 0, 0, 0);
        acc1[q] = __builtin_amdgcn_mfma_f32_16x16x32_f16(al, bhv, acc1[q], 0, 0, 0);
      }
    }
    float y[4][4];
#pragma unroll
    for (int q = 0; q < 4; ++q)
#pragma unroll
      for (int j = 0; j < 4; ++j)
        y[q][j] = acc0[q][j] + acc1[q][j] * (1.0f / 2048.0f);

    // per-WG LN stat partials -> publish as packed u64 plain device-scope stores
    float s1[4], s2[4];
#pragma unroll
    for (int j = 0; j < 4; ++j) {
      s1[j] = y[0][j] + y[1][j] + y[2][j] + y[3][j];
      s2[j] = y[0][j] * y[0][j] + y[1][j] * y[1][j] + y[2][j] * y[2][j] + y[3][j] * y[3][j];
    }
#pragma unroll
    for (int m = 1; m <= 8; m <<= 1)
#pragma unroll
      for (int j = 0; j < 4; ++j) {
        s1[j] += __shfl_xor(s1[j], m, 64);
        s2[j] += __shfl_xor(s2[j], m, 64);
      }
    if (ll == 0) {
      unsigned long long* pp = part + ((size_t)p * 32 + g) * 64 + (w * 16 + lq * 4);
#pragma unroll
      for (int j = 0; j < 4; ++j) {
        unsigned long long pv = ((unsigned long long)__builtin_bit_cast(unsigned, s2[j]) << 32) |
                                (unsigned long long)__builtin_bit_cast(unsigned, s1[j]);
        __hip_atomic_store(&pp[j], pv, __ATOMIC_RELAXED, __HIP_MEMORY_SCOPE_AGENT);
      }
    }
    // ---- barrier 1 (stats published) ----
    BAR_ARRIVE();
    BAR_WAIT();
    if (tid < 64) {
      float a1 = 0.f, a2 = 0.f;
      const unsigned long long* pp = part + (size_t)p * 2048 + tid;
#pragma unroll 8
      for (int gg = 0; gg < 32; ++gg) { // fixed order -> deterministic across WGs
        unsigned long long v = pp[(size_t)gg * 64];
        a1 += __builtin_bit_cast(float, (unsigned)v);
        a2 += __builtin_bit_cast(float, (unsigned)(v >> 32));
      }
      float mu = a1 * (1.f / 2048.f);
      float ex2 = a2 * (1.f / 2048.f);
      musd[tid] = mu;
      musd[64 + tid] = 1.0f / sqrtf(ex2 - mu * mu + 1e-5f);
    }
    __syncthreads();
    // ---- phase B: LN, gates, state update, publish h ----
    float hs[4];
#pragma unroll
    for (int j = 0; j < 4; ++j) {
      int r = w * 16 + lq * 4 + j;
      float mu = musd[r], rstd = musd[64 + r];
      float gv[4];
#pragma unroll
      for (int q = 0; q < 4; ++q)
        gv[q] = (y[q][j] - mu) * rstd * gam[q] + bet[q] + xp[q * 4 + j];
      float fi = 1.f / (1.f + expf(-gv[0]));
      float ff = 1.f / (1.f + expf(-gv[1]));
      float fo = 1.f / (1.f + expf(-gv[2]));
      float fu = tanhf(gv[3]);
      cr[j] = ff * cr[j] + fi * fu;
      float h = fo * tanhf(cr[j]);
      hs[j] = h;
      __hip_atomic_store(&hpubp[(size_t)r * 512 + hcol], split2(h),
                         __ATOMIC_RELAXED, __HIP_MEMORY_SCOPE_AGENT);
    }
    // ---- barrier 2 (h published); output stores + xp(t+1) prefetch overlap the poll ----
    BAR_ARRIVE();
#pragma unroll
    for (int j = 0; j < 4; ++j) {
      int r = w * 16 + lq * 4 + j;
      size_t ro = (size_t)r * 512 + hcol;
      __hip_atomic_store(&ys[(size_t)t * 32768 + ro], hs[j], __ATOMIC_RELAXED, __HIP_MEMORY_SCOPE_AGENT);
      if (t == 127)
        __hip_atomic_store(&cspill[ro], cr[j], __ATOMIC_RELAXED, __HIP_MEMORY_SCOPE_AGENT);
      if (t0 + t == 255) {
        __hip_atomic_store(&hn[ro], hs[j], __ATOMIC_RELAXED, __HIP_MEMORY_SCOPE_AGENT);
        __hip_atomic_store(&cn[ro], cr[j], __ATOMIC_RELAXED, __HIP_MEMORY_SCOPE_AGENT);
      }
    }
    if (t < 127) {
      const float* xrow = xn + (size_t)(t + 1) * 64 * 2048;
#pragma unroll
      for (int q = 0; q < 4; ++q)
#pragma unroll
        for (int j = 0; j < 4; ++j)
          xp[q * 4 + j] = xrow[(size_t)(w * 16 + lq * 4 + j) * 2048 + hcol + q * 512];
    }
    BAR_WAIT();
    __syncthreads();
  }
#undef BAR_ARRIVE
#undef BAR_WAIT
}

// ---- workspace layout (bytes), max ~76.3 MB ----
#define XN_OFF   0ull         // 128*64*2048 fp32 = 64MB (xn chunk)
#define WXH_OFF  67108864ull  // 2*2048*512 f16 = 4MB
#define WXL_OFF  71303168ull  // 4MB
#define WLO_OFF  75497472ull  // 2*131072*8 u16 = 4MB
#define HPP_OFF  79691776ull  // 64*512 u32 = 128KB (packed h hi|lo)
#define CSP_OFF  79822848ull  // 64*512 f32 = 128KB
#define PART_OFF 79953920ull  // 2*32*64 u64 = 32KB (LN stat partials)
#define FLG_OFF  79986688ull  // 4 regions * 2048 u32 = 32KB

extern "C" void kernel_launch(void* const* d_in, const int* in_sizes, int n_in,
                              void* d_out, int out_size, void* d_ws, size_t ws_size,
                              hipStream_t stream) {
  const float* inputs = (const float*)d_in[0];
  const float* h0 = (const float*)d_in[1];
  const float* c0 = (const float*)d_in[2];
  const float* wx = (const float*)d_in[3];
  const float* wh = (const float*)d_in[4];
  const float* bias = (const float*)d_in[5];
  const float* gx = (const float*)d_in[6];
  const float* bxp = (const float*)d_in[7];
  const float* ghp = (const float*)d_in[8];
  const float* bhp = (const float*)d_in[9];
  float* out = (float*)d_out;
  char* ws = (char*)d_ws;

  float* xn = (float*)(ws + XN_OFF);
  u16* wxh = (u16*)(ws + WXH_OFF);
  u16* wxl = (u16*)(ws + WXL_OFF);
  u16* wlo = (u16*)(ws + WLO_OFF);
  unsigned* hpp = (unsigned*)(ws + HPP_OFF);
  float* csp = (float*)(ws + CSP_OFF);
  unsigned long long* part = (unsigned long long*)(ws + PART_OFF);
  unsigned* flg = (unsigned*)(ws + FLG_OFF);

  k_zero<<<32, 256, 0, stream>>>((unsigned*)(ws + PART_OFF), flg);
  k_wsplit<<<dim3(64, 16, 2), dim3(32, 8), 0, stream>>>(wx, wxh, wxl);
  k_wlo<<<1024, 256, 0, stream>>>(wh, wlo);

  for (int l = 0; l < 2; ++l) {
    const float* Abase = (l == 0) ? inputs : out; // layer-1 input = layer-0 ys (fp32 in d_out.x)
    for (int k = 0; k < 2; ++k) {
      k_gemm3<<<dim3(16, 64), 256, 0, stream>>>(Abase + (size_t)k * 8192 * 512,
                                                wxh + (size_t)l * 2048 * 512,
                                                wxl + (size_t)l * 2048 * 512, xn, 2048, 512);
      k_ln2<<<8192, 256, 0, stream>>>(xn, gx + l * 2048, bxp + l * 2048, bias + l * 2048);
      k_scan5<<<NWG, 256, 0, stream>>>(wh + (size_t)l * 1048576, wlo + (size_t)l * 1048576,
                                       ghp + l * 2048, bhp + l * 2048, xn,
                                       h0 + (size_t)l * 32768, c0 + (size_t)l * 32768,
                                       hpp, csp, part, flg + (size_t)(l * 2 + k) * 2048,
                                       out + (size_t)k * 128 * 32768,
                                       out + 8388608 + (size_t)l * 32768,
                                       out + 8388608 + 65536 + (size_t)l * 32768,
                                       k * 128, (k == 0) ? 1 : 0);
    }
  }
}

// Round 8
// 7079.694 us; speedup vs baseline: 1.5796x; 1.5796x over previous
//
#include <hip/hip_runtime.h>

typedef unsigned short u16;
typedef _Float16 f16;
typedef __attribute__((ext_vector_type(8))) _Float16 f16x8;
typedef __attribute__((ext_vector_type(8))) unsigned short u16x8;
typedef __attribute__((ext_vector_type(4))) float f32x4;
typedef __attribute__((ext_vector_type(4))) unsigned u32x4;

#define NWG 32

// returns hi f16 bits in [15:0], lo f16 bits (residual * 2048) in [31:16]
__device__ __forceinline__ unsigned split2(float v) {
  f16 h = (f16)v;
  f16 l2 = (f16)((v - (float)h) * 2048.0f);
  return (unsigned)__builtin_bit_cast(u16, h) | ((unsigned)__builtin_bit_cast(u16, l2) << 16);
}

// ---- zero scratch control state (stat partials + flag array) ----
__global__ void k_zero(unsigned* __restrict__ part, unsigned* __restrict__ flg) {
  int i = blockIdx.x * blockDim.x + threadIdx.x;
  if (i < 8192) { part[i] = 0u; flg[i] = 0u; }
}

// ---- transpose+split wx [2][512][2048] fp32 -> wxT hi/lo [2][2048][512] f16 ----
__global__ void k_wsplit(const float* __restrict__ wx, u16* __restrict__ th, u16* __restrict__ tl) {
  __shared__ float tile[32][33];
  int l = blockIdx.z;
  int n0 = blockIdx.x * 32, k0 = blockIdx.y * 32;
  int tx = threadIdx.x, ty = threadIdx.y;
  const float* src = wx + (size_t)l * 512 * 2048;
#pragma unroll
  for (int i = 0; i < 4; ++i)
    tile[ty + i * 8][tx] = src[(size_t)(k0 + ty + i * 8) * 2048 + n0 + tx];
  __syncthreads();
  u16* dh = th + (size_t)l * 2048 * 512;
  u16* dl = tl + (size_t)l * 2048 * 512;
#pragma unroll
  for (int i = 0; i < 4; ++i) {
    unsigned s = split2(tile[tx][ty + i * 8]);
    dh[(size_t)(n0 + ty + i * 8) * 512 + k0 + tx] = (u16)s;
    dl[(size_t)(n0 + ty + i * 8) * 512 + k0 + tx] = (u16)(s >> 16);
  }
}

// ---- pack wh_lo into MFMA-B fragment order: wlo[l][g(32)][q(4)][kc(16)][lane(64)][8] ----
__global__ void k_wlo(const float* __restrict__ wh, u16* __restrict__ wlo) {
  int idx = blockIdx.x * blockDim.x + threadIdx.x; // 262144 total
  int l = idx >> 17;
  int r = idx & 131071;
  int lane = r & 63;
  int fg = r >> 6; // [0,2048)
  int kc = fg & 15, q = (fg >> 4) & 3, g = fg >> 6; // g in [0,32)
  int gcol = g * 16 + (lane & 15) + q * 512;
  int kb = kc * 32 + ((lane >> 4) << 3);
  const float* W = wh + (size_t)l * 512 * 2048;
  u16x8 o;
#pragma unroll
  for (int j = 0; j < 8; ++j)
    o[j] = (u16)(split2(W[(size_t)(kb + j) * 2048 + gcol]) >> 16);
  *(u16x8*)(wlo + (size_t)idx * 8) = o;
}

// ---- split-fp16 GEMM: A fp32 [8192,K] (split on the fly), Bt hi/lo [N,K] f16 -> C fp32 ----
__global__ void __launch_bounds__(256, 1) k_gemm3(const float* __restrict__ A,
                                                  const u16* __restrict__ Bh, const u16* __restrict__ Bl,
                                                  float* __restrict__ C, int N, int K) {
  __shared__ u16 sA[2][128 * 64];
  __shared__ u16 sB[2][128 * 64];
  const int tid = threadIdx.x, l = tid & 63, w = tid >> 6;
  const int bx = blockIdx.x, by = blockIdx.y;
  const int wr = (w >> 1) * 64, wc = (w & 1) * 64;
  f32x4 acc0[4][4] = {}, acc1[4][4] = {};
  for (int k0 = 0; k0 < K; k0 += 64) {
#pragma unroll
    for (int s = 0; s < 4; ++s) {
      int cn = s * 256 + tid;
      int row = cn >> 3;
      int f0 = (cn & 7) * 8;
      int kb = f0 * 2;
      int sw = row * 128 + (kb ^ ((row & 7) << 4));
      const float* ap = A + ((size_t)(by * 128 + row) * K + k0 + f0);
      float4 a0 = *(const float4*)ap, a1 = *(const float4*)(ap + 4);
      float av[8] = {a0.x, a0.y, a0.z, a0.w, a1.x, a1.y, a1.z, a1.w};
      u16x8 ah_, al_;
#pragma unroll
      for (int j = 0; j < 8; ++j) {
        unsigned sp = split2(av[j]);
        ah_[j] = (u16)sp;
        al_[j] = (u16)(sp >> 16);
      }
      *(u16x8*)((char*)sA[0] + sw) = ah_;
      *(u16x8*)((char*)sA[1] + sw) = al_;
      size_t gb = (((size_t)(bx * 128 + row) * K + k0) << 1) + kb;
      *(u16x8*)((char*)sB[0] + sw) = *(const u16x8*)((const char*)Bh + gb);
      *(u16x8*)((char*)sB[1] + sw) = *(const u16x8*)((const char*)Bl + gb);
    }
    __syncthreads();
#pragma unroll
    for (int kc = 0; kc < 2; ++kc) {
      int kb = kc * 64 + (l >> 4) * 16;
      f16x8 ah[4], al[4], bh[4], bl[4];
#pragma unroll
      for (int mt = 0; mt < 4; ++mt) {
        int row = wr + mt * 16 + (l & 15);
        int off = row * 128 + (kb ^ ((row & 7) << 4));
        ah[mt] = *(const f16x8*)((const char*)sA[0] + off);
        al[mt] = *(const f16x8*)((const char*)sA[1] + off);
      }
#pragma unroll
      for (int nt = 0; nt < 4; ++nt) {
        int col = wc + nt * 16 + (l & 15);
        int off = col * 128 + (kb ^ ((col & 7) << 4));
        bh[nt] = *(const f16x8*)((const char*)sB[0] + off);
        bl[nt] = *(const f16x8*)((const char*)sB[1] + off);
      }
#pragma unroll
      for (int mt = 0; mt < 4; ++mt)
#pragma unroll
        for (int nt = 0; nt < 4; ++nt) {
          acc0[mt][nt] = __builtin_amdgcn_mfma_f32_16x16x32_f16(ah[mt], bh[nt], acc0[mt][nt], 0, 0, 0);
          acc1[mt][nt] = __builtin_amdgcn_mfma_f32_16x16x32_f16(ah[mt], bl[nt], acc1[mt][nt], 0, 0, 0);
          acc1[mt][nt] = __builtin_amdgcn_mfma_f32_16x16x32_f16(al[mt], bh[nt], acc1[mt][nt], 0, 0, 0);
        }
    }
    __syncthreads();
  }
#pragma unroll
  for (int mt = 0; mt < 4; ++mt)
#pragma unroll
    for (int nt = 0; nt < 4; ++nt)
#pragma unroll
      for (int j = 0; j < 4; ++j) {
        int row = by * 128 + wr + mt * 16 + ((l >> 4) << 2) + j;
        int col = bx * 128 + wc + nt * 16 + (l & 15);
        C[(size_t)row * N + col] = acc0[mt][nt][j] + acc1[mt][nt][j] * (1.0f / 2048.0f);
      }
}

// ---- in-place fp32 row LayerNorm [rows][2048]: y = (x-mu)*rstd*g + b + bias ----
__global__ void __launch_bounds__(256) k_ln2(float* __restrict__ X, const float* __restrict__ g,
                                             const float* __restrict__ b, const float* __restrict__ bias) {
  const int row = blockIdx.x, tid = threadIdx.x;
  float* rp = X + (size_t)row * 2048 + tid * 8;
  float4 v0 = *(const float4*)rp, v1 = *(const float4*)(rp + 4);
  float x[8] = {v0.x, v0.y, v0.z, v0.w, v1.x, v1.y, v1.z, v1.w};
  float s1 = 0.f, s2 = 0.f;
#pragma unroll
  for (int j = 0; j < 8; ++j) { s1 += x[j]; s2 += x[j] * x[j]; }
#pragma unroll
  for (int m = 1; m <= 32; m <<= 1) { s1 += __shfl_xor(s1, m, 64); s2 += __shfl_xor(s2, m, 64); }
  __shared__ float a1[4], a2[4];
  if ((tid & 63) == 0) { a1[tid >> 6] = s1; a2[tid >> 6] = s2; }
  __syncthreads();
  s1 = a1[0] + a1[1] + a1[2] + a1[3];
  s2 = a2[0] + a2[1] + a2[2] + a2[3];
  float mu = s1 * (1.f / 2048.f);
  float var = s2 * (1.f / 2048.f) - mu * mu;
  float rstd = 1.0f / sqrtf(var + 1e-5f);
#pragma unroll
  for (int j = 0; j < 8; ++j) {
    int c = tid * 8 + j;
    x[j] = (x[j] - mu) * rstd * g[c] + b[c] + bias[c];
  }
  *(float4*)rp = {x[0], x[1], x[2], x[3]};
  *(float4*)(rp + 4) = {x[4], x[5], x[6], x[7]};
}

// ---- persistent LSTM scan (128-step chunk) ----
// wh_hi AND wh_lo fragments both LDS-resident (131.6KB) -> no per-step weight stream,
// and the barrier acquire-invalidate no longer evicts anything hot.
// LN stats: part[p][row][32 WGs] u64 -> writer 4 scattered stores; reader = 16 contiguous
// uint4 loads (one latency round), fixed-order sum (deterministic, atomic-free).
// Outputs (ys/cspill/hn/cn) + xp(t+1) prefetch issued after barrier-2 flag store.
__global__ void __launch_bounds__(256, 1) k_scan6(
    const float* __restrict__ wh, const u16* __restrict__ wlo,
    const float* __restrict__ gh, const float* __restrict__ bh,
    const float* __restrict__ xn, const float* __restrict__ h0l, const float* __restrict__ c0l,
    unsigned* __restrict__ hpubp, float* __restrict__ cspill,
    unsigned long long* __restrict__ part, unsigned* __restrict__ flags,
    float* __restrict__ ys, float* __restrict__ hn, float* __restrict__ cn,
    int t0, int first) {
  __shared__ u16 pk[32768]; // 64KB wh_hi fragments [q][kc][lane][8]
  __shared__ u16 wl[32768]; // 64KB wh_lo fragments (same layout)
  __shared__ float musd[128];
  const int tid = threadIdx.x;
  const int l = tid & 63, w = tid >> 6;
  const int g = blockIdx.x;
  const int lq = l >> 4, ll = l & 15;
  const int hcol = g * 16 + ll;

  // pack wh_hi into LDS; copy wh_lo fragments global->LDS
  const u16* wloG = wlo + (size_t)g * 32768;
  for (int c = tid; c < 4096; c += 256) {
    int lane = c & 63, kc = (c >> 6) & 15, q = c >> 10;
    int gcol = g * 16 + (lane & 15) + q * 512;
    int kb = kc * 32 + ((lane >> 4) << 3);
    u16x8 t8;
#pragma unroll
    for (int j = 0; j < 8; ++j)
      t8[j] = __builtin_bit_cast(u16, (f16)wh[(size_t)(kb + j) * 2048 + gcol]);
    *(u16x8*)(pk + (size_t)c * 8) = t8;
    *(u16x8*)(wl + (size_t)c * 8) = *(const u16x8*)(wloG + (size_t)c * 8);
  }
  float gam[4], bet[4];
#pragma unroll
  for (int q = 0; q < 4; ++q) { int gc = hcol + q * 512; gam[q] = gh[gc]; bet[q] = bh[gc]; }
  float cr[4];
#pragma unroll
  for (int j = 0; j < 4; ++j) {
    int r = w * 16 + lq * 4 + j;
    cr[j] = first ? c0l[r * 512 + hcol] : cspill[r * 512 + hcol];
  }
  if (first) {
    for (int u = tid; u < 1024; u += 256) {
      int row = 2 * g + (u >> 9), col = u & 511;
      __hip_atomic_store(&hpubp[row * 512 + col], split2(h0l[row * 512 + col]),
                         __ATOMIC_RELAXED, __HIP_MEMORY_SCOPE_AGENT);
    }
  }
  unsigned bid = 0;
#define BAR_ARRIVE()                                                                         \
  do {                                                                                       \
    bid++;                                                                                   \
    asm volatile("s_waitcnt vmcnt(0)" ::: "memory");                                         \
    __syncthreads();                                                                         \
    if (tid == 0)                                                                            \
      __hip_atomic_store(&flags[g * 32], bid, __ATOMIC_RELAXED, __HIP_MEMORY_SCOPE_AGENT);   \
  } while (0)
#define BAR_WAIT()                                                                           \
  do {                                                                                       \
    if (tid < NWG)                                                                           \
      while (__hip_atomic_load(&flags[tid * 32], __ATOMIC_RELAXED,                           \
                               __HIP_MEMORY_SCOPE_AGENT) < bid) {}                           \
    __builtin_amdgcn_fence(__ATOMIC_ACQUIRE, "agent");                                       \
  } while (0)

  float xp[16];
  BAR_ARRIVE();
  // prefetch xp for t=0 under the initial barrier wait
#pragma unroll
  for (int q = 0; q < 4; ++q)
#pragma unroll
    for (int j = 0; j < 4; ++j)
      xp[q * 4 + j] = xn[(size_t)(w * 16 + lq * 4 + j) * 2048 + hcol + q * 512];
  BAR_WAIT();
  __syncthreads();

  for (int t = 0; t < 128; ++t) {
    const int p = (t0 + t) & 1;
    // ---- phase A: y = h @ W (split fp16); h read packed u32, unpacked via v_perm ----
    f32x4 acc0[4] = {}, acc1[4] = {};
#pragma unroll
    for (int kc = 0; kc < 16; ++kc) {
      const unsigned* hp = hpubp + ((size_t)(w * 16 + ll) * 512 + kc * 32 + lq * 8);
      uint4 pa = *(const uint4*)hp;
      uint4 pb = *(const uint4*)(hp + 4);
      u32x4 ahw, alw;
      ahw[0] = __builtin_amdgcn_perm(pa.y, pa.x, 0x05040100u);
      ahw[1] = __builtin_amdgcn_perm(pa.w, pa.z, 0x05040100u);
      ahw[2] = __builtin_amdgcn_perm(pb.y, pb.x, 0x05040100u);
      ahw[3] = __builtin_amdgcn_perm(pb.w, pb.z, 0x05040100u);
      alw[0] = __builtin_amdgcn_perm(pa.y, pa.x, 0x07060302u);
      alw[1] = __builtin_amdgcn_perm(pa.w, pa.z, 0x07060302u);
      alw[2] = __builtin_amdgcn_perm(pb.y, pb.x, 0x07060302u);
      alw[3] = __builtin_amdgcn_perm(pb.w, pb.z, 0x07060302u);
      f16x8 ah = __builtin_bit_cast(f16x8, ahw);
      f16x8 al = __builtin_bit_cast(f16x8, alw);
#pragma unroll
      for (int q = 0; q < 4; ++q) {
        f16x8 bhv = *(const f16x8*)(pk + ((size_t)(q * 16 + kc) * 64 + l) * 8);
        f16x8 blv = *(const f16x8*)(wl + ((size_t)(q * 16 + kc) * 64 + l) * 8);
        acc0[q] = __builtin_amdgcn_mfma_f32_16x16x32_f16(ah, bhv, acc0[q], 0, 0, 0);
        acc1[q] = __builtin_amdgcn_mfma_f32_16x16x32_f16(ah, blv, acc1[q], 0, 0, 0);
        acc1[q] = __builtin_amdgcn_mfma_f32_16x16x32_f16(al, bhv, acc1[q], 0, 0, 0);
      }
    }
    float y[4][4];
#pragma unroll
    for (int q = 0; q < 4; ++q)
#pragma unroll
      for (int j = 0; j < 4; ++j)
        y[q][j] = acc0[q][j] + acc1[q][j] * (1.0f / 2048.0f);

    // per-WG LN partials -> part[p][row][g] (plain device-scope u64 stores)
    float s1[4], s2[4];
#pragma unroll
    for (int j = 0; j < 4; ++j) {
      s1[j] = y[0][j] + y[1][j] + y[2][j] + y[3][j];
      s2[j] = y[0][j] * y[0][j] + y[1][j] * y[1][j] + y[2][j] * y[2][j] + y[3][j] * y[3][j];
    }
#pragma unroll
    for (int m = 1; m <= 8; m <<= 1)
#pragma unroll
      for (int j = 0; j < 4; ++j) {
        s1[j] += __shfl_xor(s1[j], m, 64);
        s2[j] += __shfl_xor(s2[j], m, 64);
      }
    if (ll == 0) {
#pragma unroll
      for (int j = 0; j < 4; ++j) {
        int r = w * 16 + lq * 4 + j;
        unsigned long long pv = ((unsigned long long)__builtin_bit_cast(unsigned, s2[j]) << 32) |
                                (unsigned long long)__builtin_bit_cast(unsigned, s1[j]);
        __hip_atomic_store(&part[(size_t)p * 2048 + (size_t)r * 32 + g], pv,
                           __ATOMIC_RELAXED, __HIP_MEMORY_SCOPE_AGENT);
      }
    }
    // ---- barrier 1 (stats published) ----
    BAR_ARRIVE();
    BAR_WAIT();
    if (tid < 64) {
      // row tid: 32 partials = 256B contiguous = 16 uint4 loads, one latency round
      const uint4* pp = (const uint4*)(part + (size_t)p * 2048 + (size_t)tid * 32);
      float a1 = 0.f, a2 = 0.f;
#pragma unroll
      for (int i = 0; i < 16; ++i) { // fixed order g=0..31 -> deterministic
        uint4 v = pp[i];
        a1 += __builtin_bit_cast(float, v.x);
        a2 += __builtin_bit_cast(float, v.y);
        a1 += __builtin_bit_cast(float, v.z);
        a2 += __builtin_bit_cast(float, v.w);
      }
      float mu = a1 * (1.f / 2048.f);
      float ex2 = a2 * (1.f / 2048.f);
      musd[tid] = mu;
      musd[64 + tid] = 1.0f / sqrtf(ex2 - mu * mu + 1e-5f);
    }
    __syncthreads();
    // ---- phase B: LN, gates, state update, publish h ----
    float hs[4];
#pragma unroll
    for (int j = 0; j < 4; ++j) {
      int r = w * 16 + lq * 4 + j;
      float mu = musd[r], rstd = musd[64 + r];
      float gv[4];
#pragma unroll
      for (int q = 0; q < 4; ++q)
        gv[q] = (y[q][j] - mu) * rstd * gam[q] + bet[q] + xp[q * 4 + j];
      float fi = 1.f / (1.f + expf(-gv[0]));
      float ff = 1.f / (1.f + expf(-gv[1]));
      float fo = 1.f / (1.f + expf(-gv[2]));
      float fu = tanhf(gv[3]);
      cr[j] = ff * cr[j] + fi * fu;
      float h = fo * tanhf(cr[j]);
      hs[j] = h;
      __hip_atomic_store(&hpubp[(size_t)r * 512 + hcol], split2(h),
                         __ATOMIC_RELAXED, __HIP_MEMORY_SCOPE_AGENT);
    }
    // ---- barrier 2 (h published); output stores + xp(t+1) prefetch overlap the poll ----
    BAR_ARRIVE();
#pragma unroll
    for (int j = 0; j < 4; ++j) {
      int r = w * 16 + lq * 4 + j;
      size_t ro = (size_t)r * 512 + hcol;
      __hip_atomic_store(&ys[(size_t)t * 32768 + ro], hs[j], __ATOMIC_RELAXED, __HIP_MEMORY_SCOPE_AGENT);
      if (t == 127)
        __hip_atomic_store(&cspill[ro], cr[j], __ATOMIC_RELAXED, __HIP_MEMORY_SCOPE_AGENT);
      if (t0 + t == 255) {
        __hip_atomic_store(&hn[ro], hs[j], __ATOMIC_RELAXED, __HIP_MEMORY_SCOPE_AGENT);
        __hip_atomic_store(&cn[ro], cr[j], __ATOMIC_RELAXED, __HIP_MEMORY_SCOPE_AGENT);
      }
    }
    if (t < 127) {
      const float* xrow = xn + (size_t)(t + 1) * 64 * 2048;
#pragma unroll
      for (int q = 0; q < 4; ++q)
#pragma unroll
        for (int j = 0; j < 4; ++j)
          xp[q * 4 + j] = xrow[(size_t)(w * 16 + lq * 4 + j) * 2048 + hcol + q * 512];
    }
    BAR_WAIT();
    __syncthreads();
  }
#undef BAR_ARRIVE
#undef BAR_WAIT
}

// ---- workspace layout (bytes), max ~76.3 MB ----
#define XN_OFF   0ull         // 128*64*2048 fp32 = 64MB (xn chunk)
#define WXH_OFF  67108864ull  // 2*2048*512 f16 = 4MB
#define WXL_OFF  71303168ull  // 4MB
#define WLO_OFF  75497472ull  // 2*131072*8 u16 = 4MB
#define HPP_OFF  79691776ull  // 64*512 u32 = 128KB (packed h hi|lo)
#define CSP_OFF  79822848ull  // 64*512 f32 = 128KB
#define PART_OFF 79953920ull  // 2*64*32 u64 = 32KB (LN stat partials, [p][row][g])
#define FLG_OFF  79986688ull  // 4 regions * 2048 u32 = 32KB

extern "C" void kernel_launch(void* const* d_in, const int* in_sizes, int n_in,
                              void* d_out, int out_size, void* d_ws, size_t ws_size,
                              hipStream_t stream) {
  const float* inputs = (const float*)d_in[0];
  const float* h0 = (const float*)d_in[1];
  const float* c0 = (const float*)d_in[2];
  const float* wx = (const float*)d_in[3];
  const float* wh = (const float*)d_in[4];
  const float* bias = (const float*)d_in[5];
  const float* gx = (const float*)d_in[6];
  const float* bxp = (const float*)d_in[7];
  const float* ghp = (const float*)d_in[8];
  const float* bhp = (const float*)d_in[9];
  float* out = (float*)d_out;
  char* ws = (char*)d_ws;

  float* xn = (float*)(ws + XN_OFF);
  u16* wxh = (u16*)(ws + WXH_OFF);
  u16* wxl = (u16*)(ws + WXL_OFF);
  u16* wlo = (u16*)(ws + WLO_OFF);
  unsigned* hpp = (unsigned*)(ws + HPP_OFF);
  float* csp = (float*)(ws + CSP_OFF);
  unsigned long long* part = (unsigned long long*)(ws + PART_OFF);
  unsigned* flg = (unsigned*)(ws + FLG_OFF);

  k_zero<<<32, 256, 0, stream>>>((unsigned*)(ws + PART_OFF), flg);
  k_wsplit<<<dim3(64, 16, 2), dim3(32, 8), 0, stream>>>(wx, wxh, wxl);
  k_wlo<<<1024, 256, 0, stream>>>(wh, wlo);

  for (int l = 0; l < 2; ++l) {
    const float* Abase = (l == 0) ? inputs : out; // layer-1 input = layer-0 ys (fp32 in d_out.x)
    for (int k = 0; k < 2; ++k) {
      k_gemm3<<<dim3(16, 64), 256, 0, stream>>>(Abase + (size_t)k * 8192 * 512,
                                                wxh + (size_t)l * 2048 * 512,
                                                wxl + (size_t)l * 2048 * 512, xn, 2048, 512);
      k_ln2<<<8192, 256, 0, stream>>>(xn, gx + l * 2048, bxp + l * 2048, bias + l * 2048);
      k_scan6<<<NWG, 256, 0, stream>>>(wh + (size_t)l * 1048576, wlo + (size_t)l * 1048576,
                                       ghp + l * 2048, bhp + l * 2048, xn,
                                       h0 + (size_t)l * 32768, c0 + (size_t)l * 32768,
                                       hpp, csp, part, flg + (size_t)(l * 2 + k) * 2048,
                                       out + (size_t)k * 128 * 32768,
                                       out + 8388608 + (size_t)l * 32768,
                                       out + 8388608 + 65536 + (size_t)l * 32768,
                                       k * 128, (k == 0) ? 1 : 0);
    }
  }
}